// Round 1
// baseline (79.003 us; speedup 1.0000x reference)
//
#include <hip/hip_runtime.h>

#define NB 512      // batch
#define ND 128      // dim
#define TALPHA 0.2f

// One block per anchor 'a'. 256 threads.
__global__ __launch_bounds__(256) void triplet_mine_kernel(
    const float* __restrict__ x,       // [NB][ND]
    const int*   __restrict__ target,  // [NB]
    const float* __restrict__ noise,   // [NB][NB][NB]
    float*       __restrict__ partial) // [NB]
{
    const int a   = blockIdx.x;
    const int tid = threadIdx.x;
    const int lane = tid & 63;
    const int wv   = tid >> 6;          // 0..3

    __shared__ float d_row[NB];   // d[a][n]
    __shared__ int   tgt[NB];
    __shared__ float xa[ND];
    __shared__ float red_s[4];
    __shared__ int   red_i[4];

    // stage targets and anchor embedding
    tgt[tid]       = target[tid];
    tgt[tid + 256] = target[tid + 256];
    if (tid < ND) xa[tid] = x[(size_t)a * ND + tid];
    __syncthreads();

    const int ta = tgt[a];

    // compute d[a][n] for n = tid, tid+256
    #pragma unroll
    for (int nn = 0; nn < 2; ++nn) {
        const int n = tid + nn * 256;
        const float* xr = x + (size_t)n * ND;
        float acc = 0.0f;
        #pragma unroll
        for (int k = 0; k < ND; k += 4) {
            float4 v = *reinterpret_cast<const float4*>(xr + k);
            acc += xa[k]   * v.x;
            acc += xa[k+1] * v.y;
            acc += xa[k+2] * v.z;
            acc += xa[k+3] * v.w;
        }
        d_row[n] = 2.0f - 2.0f * acc;
    }
    __syncthreads();

    float acc_loss = 0.0f;   // only thread 0's value is used

    // serial p loop: uniform branch (all data in LDS)
    for (int p = 0; p < NB; ++p) {
        if (p == a || tgt[p] != ta) continue;

        const float d_ap = d_row[p];
        const float* nrow = noise + ((size_t)a * NB + (size_t)p) * NB;

        // each thread evaluates n = tid and n = tid+256
        float best_s; int best_n;
        {
            const int n0 = tid;
            const float L0 = d_ap - d_row[n0] + TALPHA;
            const bool c0 = (L0 > 0.0f) & (L0 < TALPHA) & (tgt[n0] != ta);
            const float v0 = nrow[n0];
            best_s = c0 ? v0 : -1.0f;
            best_n = n0;

            const int n1 = tid + 256;
            const float L1 = d_ap - d_row[n1] + TALPHA;
            const bool c1 = (L1 > 0.0f) & (L1 < TALPHA) & (tgt[n1] != ta);
            const float v1 = nrow[n1];
            const float s1 = c1 ? v1 : -1.0f;
            // prefer higher score; tie -> lower index (n0 < n1 always, keep n0 on tie)
            if (s1 > best_s) { best_s = s1; best_n = n1; }
        }

        // wave(64)-level argmax reduce, tie -> lower index
        #pragma unroll
        for (int off = 32; off > 0; off >>= 1) {
            const float os = __shfl_down(best_s, off);
            const int   on = __shfl_down(best_n, off);
            if (os > best_s || (os == best_s && on < best_n)) {
                best_s = os; best_n = on;
            }
        }
        if (lane == 0) { red_s[wv] = best_s; red_i[wv] = best_n; }
        __syncthreads();

        if (tid == 0) {
            float bs = red_s[0]; int bn = red_i[0];
            #pragma unroll
            for (int w = 1; w < 4; ++w) {
                const float os = red_s[w]; const int on = red_i[w];
                if (os > bs || (os == bs && on < bn)) { bs = os; bn = on; }
            }
            if (bs >= 0.0f) {  // has_cand (noise in [0,1), non-candidates are -1)
                const float L = d_ap - d_row[bn] + TALPHA;
                // L in (0, ALPHA) by construction; max(L,0) == L
                acc_loss += L;
            }
        }
        __syncthreads();   // protect red_s/red_i before next pair
    }

    if (tid == 0) partial[a] = acc_loss;
}

// deterministic tree-sum of 512 partials
__global__ __launch_bounds__(512) void triplet_reduce_kernel(
    const float* __restrict__ partial, float* __restrict__ out)
{
    __shared__ float s[NB];
    const int t = threadIdx.x;
    s[t] = partial[t];
    __syncthreads();
    #pragma unroll
    for (int off = 256; off > 0; off >>= 1) {
        if (t < off) s[t] += s[t + off];
        __syncthreads();
    }
    if (t == 0) out[0] = s[0];
}

extern "C" void kernel_launch(void* const* d_in, const int* in_sizes, int n_in,
                              void* d_out, int out_size, void* d_ws, size_t ws_size,
                              hipStream_t stream) {
    const float* x      = (const float*)d_in[0];
    const int*   target = (const int*)d_in[1];
    const float* noise  = (const float*)d_in[2];
    float* out     = (float*)d_out;
    float* partial = (float*)d_ws;   // 512 floats

    triplet_mine_kernel<<<NB, 256, 0, stream>>>(x, target, noise, partial);
    triplet_reduce_kernel<<<1, NB, 0, stream>>>(partial, out);
}

// Round 2
// 28.009 us; speedup vs baseline: 2.8206x; 2.8206x over previous
//
#include <hip/hip_runtime.h>

#define NB 512      // batch
#define ND 128      // dim
#define TALPHA 0.2f

// One block per anchor 'a'. 512 threads = 8 waves.
// Wave w handles positives plist[w], plist[w+8], ... fully independently.
__global__ __launch_bounds__(512) void triplet_mine_kernel(
    const float* __restrict__ x,       // [NB][ND]
    const int*   __restrict__ target,  // [NB]
    const float* __restrict__ noise,   // [NB][NB][NB]
    float*       __restrict__ partial) // [NB]
{
    const int a    = blockIdx.x;
    const int tid  = threadIdx.x;
    const int lane = tid & 63;
    const int wv   = tid >> 6;          // 0..7

    __shared__ __align__(16) float d_row[NB];   // d[a][n]
    __shared__ __align__(16) int   tgt[NB];
    __shared__ float xa[ND];
    __shared__ int   plist[NB];
    __shared__ int   pcnt_w[8];
    __shared__ float wacc_s[8];

    // stage targets + anchor embedding
    tgt[tid] = target[tid];
    if (tid < ND) xa[tid] = x[(size_t)a * ND + tid];
    __syncthreads();

    const int ta = tgt[a];

    // d[a][tid] — one row element per thread
    {
        const float* xr = x + (size_t)tid * ND;
        float acc = 0.0f;
        #pragma unroll
        for (int k = 0; k < ND; k += 4) {
            float4 v = *reinterpret_cast<const float4*>(xr + k);
            acc += xa[k]   * v.x;
            acc += xa[k+1] * v.y;
            acc += xa[k+2] * v.z;
            acc += xa[k+3] * v.w;
        }
        d_row[tid] = 2.0f - 2.0f * acc;
    }

    // ballot-compact the positive list (n: tgt[n]==ta, n!=a)
    const bool m = (tgt[tid] == ta) && (tid != a);
    const unsigned long long b = __ballot(m);
    if (lane == 0) pcnt_w[wv] = __popcll(b);
    __syncthreads();   // d_row + pcnt_w visible

    int base = 0;
    for (int w = 0; w < wv; ++w) base += pcnt_w[w];
    if (m) {
        const unsigned long long lower = b & ((1ull << lane) - 1ull);
        plist[base + __popcll(lower)] = tid;
    }
    __syncthreads();

    int npos = 0;
    #pragma unroll
    for (int w = 0; w < 8; ++w) npos += pcnt_w[w];

    // per-wave argmax over 512 candidates: 8 per lane (two float4 groups)
    float wacc = 0.0f;
    const float4* d4  = reinterpret_cast<const float4*>(d_row);
    const int4*   t4  = reinterpret_cast<const int4*>(tgt);

    for (int idx = wv; idx < npos; idx += 8) {
        const int p = plist[idx];
        const float d_ap = d_row[p];
        const float* nrow = noise + ((size_t)a * NB + (size_t)p) * NB;

        const float4 nv0 = *reinterpret_cast<const float4*>(nrow + 4 * lane);
        const float4 nv1 = *reinterpret_cast<const float4*>(nrow + 256 + 4 * lane);
        const float4 dd0 = d4[lane];
        const float4 dd1 = d4[64 + lane];
        const int4   tt0 = t4[lane];
        const int4   tt1 = t4[64 + lane];

        float bs = -1.0f;      // non-candidate sentinel (noise >= 0)
        int   bn = NB;         // large index so ties at -1 are irrelevant

        // iterate in ascending-n order within the lane; strict > keeps lowest n
        #define EVAL(nn, dn, tn, sv)                                   \
        {                                                              \
            const float L = d_ap - (dn) + TALPHA;                      \
            if ((L > 0.0f) & (L < TALPHA) & ((tn) != ta)) {            \
                if ((sv) > bs) { bs = (sv); bn = (nn); }               \
            }                                                          \
        }
        EVAL(4*lane + 0,       dd0.x, tt0.x, nv0.x);
        EVAL(4*lane + 1,       dd0.y, tt0.y, nv0.y);
        EVAL(4*lane + 2,       dd0.z, tt0.z, nv0.z);
        EVAL(4*lane + 3,       dd0.w, tt0.w, nv0.w);
        EVAL(256 + 4*lane + 0, dd1.x, tt1.x, nv1.x);
        EVAL(256 + 4*lane + 1, dd1.y, tt1.y, nv1.y);
        EVAL(256 + 4*lane + 2, dd1.z, tt1.z, nv1.z);
        EVAL(256 + 4*lane + 3, dd1.w, tt1.w, nv1.w);
        #undef EVAL

        // butterfly argmax across 64 lanes; tie -> lower n (matches jnp.argmax)
        #pragma unroll
        for (int off = 1; off < 64; off <<= 1) {
            const float os = __shfl_xor(bs, off);
            const int   on = __shfl_xor(bn, off);
            if (os > bs || (os == bs && on < bn)) { bs = os; bn = on; }
        }

        if (bs >= 0.0f) {      // has_cand
            wacc += d_ap - d_row[bn] + TALPHA;   // L in (0, ALPHA): max(L,0)==L
        }
    }

    if (lane == 0) wacc_s[wv] = wacc;
    __syncthreads();
    if (tid == 0) {
        float s = 0.0f;
        #pragma unroll
        for (int w = 0; w < 8; ++w) s += wacc_s[w];
        partial[a] = s;
    }
}

// deterministic single-wave reduction of 512 partials
__global__ __launch_bounds__(64) void triplet_reduce_kernel(
    const float* __restrict__ partial, float* __restrict__ out)
{
    const int lane = threadIdx.x;
    float s = 0.0f;
    #pragma unroll
    for (int j = 0; j < 8; ++j) s += partial[lane + 64 * j];
    #pragma unroll
    for (int off = 1; off < 64; off <<= 1) s += __shfl_xor(s, off);
    if (lane == 0) out[0] = s;
}

extern "C" void kernel_launch(void* const* d_in, const int* in_sizes, int n_in,
                              void* d_out, int out_size, void* d_ws, size_t ws_size,
                              hipStream_t stream) {
    const float* x      = (const float*)d_in[0];
    const int*   target = (const int*)d_in[1];
    const float* noise  = (const float*)d_in[2];
    float* out     = (float*)d_out;
    float* partial = (float*)d_ws;   // 512 floats of scratch

    triplet_mine_kernel<<<NB, 512, 0, stream>>>(x, target, noise, partial);
    triplet_reduce_kernel<<<1, 64, 0, stream>>>(partial, out);
}

// Round 3
// 15.479 us; speedup vs baseline: 5.1039x; 1.8095x over previous
//
#include <hip/hip_runtime.h>

#define NB 512      // batch
#define ND 128      // dim
#define TALPHA 0.2f

// One block per anchor 'a'. 512 threads = 8 waves.
__global__ __launch_bounds__(512) void triplet_mine_kernel(
    const float* __restrict__ x,       // [NB][ND]
    const int*   __restrict__ target,  // [NB]
    const float* __restrict__ noise,   // [NB][NB][NB]
    float*       __restrict__ partial) // [NB]
{
    const int a    = blockIdx.x;
    const int tid  = threadIdx.x;
    const int lane = tid & 63;
    const int wv   = tid >> 6;          // 0..7

    __shared__ __align__(16) float d_row[NB];   // d[a][n]
    __shared__ __align__(16) int   tgt[NB];
    __shared__ int   plist[NB];
    __shared__ int   pcnt_w[8];
    __shared__ float wacc_s[8];

    const int t_mine = target[tid];
    const int ta     = target[a];       // broadcast load
    tgt[tid] = t_mine;

    // ---- ballot-compact positives (targets only; no d dependence) ----
    const bool m = (t_mine == ta) && (tid != a);
    const unsigned long long b = __ballot(m);
    if (lane == 0) pcnt_w[wv] = __popcll(b);
    __syncthreads();

    int base = 0, npos = 0;
    #pragma unroll
    for (int w = 0; w < 8; ++w) {
        base += (w < wv) ? pcnt_w[w] : 0;
        npos += pcnt_w[w];
    }
    if (m) {
        const unsigned long long lower = b & ((1ull << lane) - 1ull);
        plist[base + __popcll(lower)] = tid;
    }
    __syncthreads();

    // ---- prefetch this wave's first noise row (hides HBM under d-compute) ----
    float4 nv0, nv1;
    if (wv < npos) {
        const int p0 = plist[wv];
        const float* nr = noise + ((size_t)a * NB + (size_t)p0) * NB;
        nv0 = *reinterpret_cast<const float4*>(nr + 4 * lane);
        nv1 = *reinterpret_cast<const float4*>(nr + 256 + 4 * lane);
    }

    // ---- coalesced d-row compute ----
    // quad of lanes per row: c = k-quarter, rgrp = row-in-group-of-16.
    // At fixed j, lanes c=0..3 read 64B contiguous; 16 rows at 512B stride
    // -> every 64B line fetched once and fully consumed.
    const int c    = lane & 3;
    const int rgrp = lane >> 2;
    const float4* xf4 = reinterpret_cast<const float4*>(x);

    float4 xa4[8];
    #pragma unroll
    for (int j = 0; j < 8; ++j) xa4[j] = xf4[(size_t)a * 32 + j * 4 + c];

    #pragma unroll
    for (int q = 0; q < 4; ++q) {
        const int row = q * 128 + wv * 16 + rgrp;
        const float4* rf4 = xf4 + (size_t)row * 32;
        float acc = 0.0f;
        #pragma unroll
        for (int j = 0; j < 8; ++j) {
            const float4 v = rf4[j * 4 + c];
            acc += xa4[j].x * v.x + xa4[j].y * v.y
                 + xa4[j].z * v.z + xa4[j].w * v.w;
        }
        acc += __shfl_xor(acc, 1);   // combine the quad's partial dots
        acc += __shfl_xor(acc, 2);
        if (c == 0) d_row[row] = 2.0f - 2.0f * acc;
    }
    __syncthreads();

    // ---- per-wave semi-hard mining; one positive per wave per iteration ----
    float wacc = 0.0f;
    const float4* d4 = reinterpret_cast<const float4*>(d_row);
    const int4*   t4 = reinterpret_cast<const int4*>(tgt);
    const float4 dd0 = d4[lane];
    const float4 dd1 = d4[64 + lane];
    const int4   tt0 = t4[lane];
    const int4   tt1 = t4[64 + lane];

    for (int idx = wv; idx < npos; idx += 8) {
        // prefetch next iteration's noise row
        float4 nx0, nx1;
        const int nidx = idx + 8;
        if (nidx < npos) {
            const int pn = plist[nidx];
            const float* nr = noise + ((size_t)a * NB + (size_t)pn) * NB;
            nx0 = *reinterpret_cast<const float4*>(nr + 4 * lane);
            nx1 = *reinterpret_cast<const float4*>(nr + 256 + 4 * lane);
        }

        const int p = plist[idx];
        const float d_ap = d_row[p];

        float bs = -1.0f;   // non-candidate sentinel (noise >= 0)
        int   bn = NB;

        // ascending-n order within lane; strict > keeps lowest n on ties
        #define EVAL(nn, dn, tn, sv)                                   \
        {                                                              \
            const float L = d_ap - (dn) + TALPHA;                      \
            if ((L > 0.0f) & (L < TALPHA) & ((tn) != ta)) {            \
                if ((sv) > bs) { bs = (sv); bn = (nn); }               \
            }                                                          \
        }
        EVAL(4*lane + 0,       dd0.x, tt0.x, nv0.x);
        EVAL(4*lane + 1,       dd0.y, tt0.y, nv0.y);
        EVAL(4*lane + 2,       dd0.z, tt0.z, nv0.z);
        EVAL(4*lane + 3,       dd0.w, tt0.w, nv0.w);
        EVAL(256 + 4*lane + 0, dd1.x, tt1.x, nv1.x);
        EVAL(256 + 4*lane + 1, dd1.y, tt1.y, nv1.y);
        EVAL(256 + 4*lane + 2, dd1.z, tt1.z, nv1.z);
        EVAL(256 + 4*lane + 3, dd1.w, tt1.w, nv1.w);
        #undef EVAL

        // butterfly argmax across 64 lanes; tie -> lower n (jnp.argmax order)
        #pragma unroll
        for (int off = 1; off < 64; off <<= 1) {
            const float os = __shfl_xor(bs, off);
            const int   on = __shfl_xor(bn, off);
            if (os > bs || (os == bs && on < bn)) { bs = os; bn = on; }
        }

        if (bs >= 0.0f) {   // has_cand
            wacc += d_ap - d_row[bn] + TALPHA;   // L in (0, ALPHA)
        }

        nv0 = nx0; nv1 = nx1;
    }

    if (lane == 0) wacc_s[wv] = wacc;
    __syncthreads();
    if (tid == 0) {
        float s = 0.0f;
        #pragma unroll
        for (int w = 0; w < 8; ++w) s += wacc_s[w];
        partial[a] = s;
    }
}

// deterministic single-wave reduction of 512 partials
__global__ __launch_bounds__(64) void triplet_reduce_kernel(
    const float* __restrict__ partial, float* __restrict__ out)
{
    const int lane = threadIdx.x;
    float s = 0.0f;
    #pragma unroll
    for (int j = 0; j < 8; ++j) s += partial[lane + 64 * j];
    #pragma unroll
    for (int off = 1; off < 64; off <<= 1) s += __shfl_xor(s, off);
    if (lane == 0) out[0] = s;
}

extern "C" void kernel_launch(void* const* d_in, const int* in_sizes, int n_in,
                              void* d_out, int out_size, void* d_ws, size_t ws_size,
                              hipStream_t stream) {
    const float* x      = (const float*)d_in[0];
    const int*   target = (const int*)d_in[1];
    const float* noise  = (const float*)d_in[2];
    float* out     = (float*)d_out;
    float* partial = (float*)d_ws;   // 512 floats of scratch

    triplet_mine_kernel<<<NB, 512, 0, stream>>>(x, target, noise, partial);
    triplet_reduce_kernel<<<1, 64, 0, stream>>>(partial, out);
}